// Round 7
// baseline (1005.204 us; speedup 1.0000x reference)
//
#include <hip/hip_runtime.h>
#include <hip/hip_bf16.h>
#include <stdint.h>

#define SEQ    2048
#define HIDDEN 4096
#define INTER  11008

typedef short bf16x8 __attribute__((ext_vector_type(8)));
typedef float f32x4  __attribute__((ext_vector_type(4)));
typedef unsigned short u16x8 __attribute__((ext_vector_type(8)));

#define BAR()  asm volatile("s_barrier" ::: "memory")
#define W6()   asm volatile("s_waitcnt vmcnt(6)" ::: "memory")
#define W4()   asm volatile("s_waitcnt vmcnt(4)" ::: "memory")
#define W3()   asm volatile("s_waitcnt vmcnt(3)" ::: "memory")
#define W2()   asm volatile("s_waitcnt vmcnt(2)" ::: "memory")
#define W0()   asm volatile("s_waitcnt vmcnt(0)" ::: "memory")

__device__ __forceinline__ unsigned short f2bf(float f) {
    union { __hip_bfloat16 h; unsigned short u; } v;
    v.h = __float2bfloat16(f);
    return v.u;
}

__device__ __forceinline__ void gload_lds16(const void* g, void* lds) {
    __builtin_amdgcn_global_load_lds(
        (const __attribute__((address_space(1))) uint32_t*)g,
        (__attribute__((address_space(3))) uint32_t*)lds,
        16, 0, 0);
}

// ---------------------------------------------------------------------------
// x fp32 -> bf16
// ---------------------------------------------------------------------------
__global__ __launch_bounds__(256) void k_cvt_x(const float* __restrict__ x,
                                               unsigned short* __restrict__ xb) {
    int i = (blockIdx.x * 256 + threadIdx.x) * 4;
    float4 v = *(const float4*)(x + i);
    ushort4 o;
    o.x = f2bf(v.x); o.y = f2bf(v.y); o.z = f2bf(v.z); o.w = f2bf(v.w);
    *(ushort4*)(xb + i) = o;
}

// ---------------------------------------------------------------------------
// Weight dequant: int32 codes -> bf16. 8 codes/thread. group = i>>7.
// ---------------------------------------------------------------------------
__global__ __launch_bounds__(256) void k_dequant(
    const int* __restrict__ qw, const int* __restrict__ qz,
    const float* __restrict__ sc, unsigned short* __restrict__ w)
{
    size_t i = ((size_t)blockIdx.x * 256 + threadIdx.x) * 8;
    int gi = (int)(i >> 7);
    int   z = qz[gi];
    float s = sc[gi];
    float zs = -(float)z * s;
    int4 q0 = *(const int4*)(qw + i);
    int4 q1 = *(const int4*)(qw + i + 4);
    u16x8 o;
    o[0] = f2bf(fmaf((float)q0.x, s, zs));
    o[1] = f2bf(fmaf((float)q0.y, s, zs));
    o[2] = f2bf(fmaf((float)q0.z, s, zs));
    o[3] = f2bf(fmaf((float)q0.w, s, zs));
    o[4] = f2bf(fmaf((float)q1.x, s, zs));
    o[5] = f2bf(fmaf((float)q1.y, s, zs));
    o[6] = f2bf(fmaf((float)q1.z, s, zs));
    o[7] = f2bf(fmaf((float)q1.w, s, zs));
    *(u16x8*)(w + i) = o;
}

// ---------------------------------------------------------------------------
// Half-K (K=32) tile layout, 128 rows x 64 B, stored as 64 storage-rows of
// 128 B (row-pairs interleaved) with XOR swizzle for conflict-free b128 reads:
//   chunk idx -> srow=idx>>3, s=idx&7, sl=s^(srow&7),
//                logical row = srow*2+(sl>>2), byte col = (sl&3)*16
// Read (row, c4=lane>>4): s = (((row&1)<<2)|c4) ^ ((row>>1)&7),
//                         off = (row>>1)*128 + s*16
// ---------------------------------------------------------------------------

// Fused gate+up GEMM + SwiGLU -> h (bf16).
// 512 thr (8 waves: 2M x 4N), tile 128x128, ring-3 of half-K phases (72 KB),
// counted vmcnt(6) (3 loads/phase/thread), raw barriers. 2 blocks/CU.
__global__ __launch_bounds__(512) void k_gate_up(
    const unsigned short* __restrict__ xb,   // [SEQ][HIDDEN] bf16
    const unsigned short* __restrict__ wg,   // [INTER][HIDDEN] bf16
    const unsigned short* __restrict__ wu,   // [INTER][HIDDEN] bf16
    const float* __restrict__ gbias, const float* __restrict__ ubias,
    unsigned short* __restrict__ h)          // [SEQ][INTER] bf16
{
    __shared__ __align__(16) unsigned short A_[3][128 * 32];   // 3 x 8 KB
    __shared__ __align__(16) unsigned short Bg_[3][128 * 32];  // 3 x 8 KB
    __shared__ __align__(16) unsigned short Bu_[3][128 * 32];  // 3 x 8 KB

    const int orig = blockIdx.x;                  // 1376 = 8 * 172
    const int swz  = (orig & 7) * 172 + (orig >> 3);
    const int mt   = swz & 15;                    // M-siblings adjacent
    const int nt   = swz >> 4;
    const int m0   = mt * 128;
    const int n0   = nt * 128;

    const int t    = threadIdx.x;
    const int lane = t & 63;
    const int wave = t >> 6;
    const int wm = (wave >> 2) * 64;
    const int wn = (wave & 3) * 32;

    // stage-side mapping (chunk idx = t, same for all 3 arrays)
    const int srow = t >> 3;
    const int sl   = (t & 7) ^ (srow & 7);
    const int lrow = srow * 2 + (sl >> 2);
    const int lcolb = (sl & 3) * 16;              // byte offset in 64B half-row

    // read-side swizzle term (per-thread constant)
    const int sS   = ((((lane & 1) << 2) | (lane >> 4)) ^ ((lane >> 1) & 7)) * 16;
    const int lrh  = (lane & 15) >> 1;

    f32x4 accG[4][2], accU[4][2];
#pragma unroll
    for (int mi = 0; mi < 4; ++mi)
#pragma unroll
        for (int ni = 0; ni < 2; ++ni) {
            accG[mi][ni] = (f32x4){0.f, 0.f, 0.f, 0.f};
            accU[mi][ni] = (f32x4){0.f, 0.f, 0.f, 0.f};
        }

    auto stage = [&](int buf, int ph) {
        const int k0 = ph * 32;
        const char* xs = (const char*)(xb + (size_t)(m0 + lrow) * HIDDEN + k0) + lcolb;
        const char* gs = (const char*)(wg + (size_t)(n0 + lrow) * HIDDEN + k0) + lcolb;
        const char* us = (const char*)(wu + (size_t)(n0 + lrow) * HIDDEN + k0) + lcolb;
        gload_lds16(xs, (char*)A_[buf]  + t * 16);
        gload_lds16(gs, (char*)Bg_[buf] + t * 16);
        gload_lds16(us, (char*)Bu_[buf] + t * 16);
    };

    auto comp = [&](int buf) {
        bf16x8 af[4], bg[2], bu[2];
#pragma unroll
        for (int mi = 0; mi < 4; ++mi)
            af[mi] = *(const bf16x8*)((const char*)A_[buf] +
                        (wm / 2 + mi * 8 + lrh) * 128 + sS);
#pragma unroll
        for (int ni = 0; ni < 2; ++ni) {
            int off = (wn / 2 + ni * 8 + lrh) * 128 + sS;
            bg[ni] = *(const bf16x8*)((const char*)Bg_[buf] + off);
            bu[ni] = *(const bf16x8*)((const char*)Bu_[buf] + off);
        }
        __builtin_amdgcn_s_setprio(1);
#pragma unroll
        for (int mi = 0; mi < 4; ++mi)
#pragma unroll
            for (int ni = 0; ni < 2; ++ni) {
                accG[mi][ni] = __builtin_amdgcn_mfma_f32_16x16x32_bf16(
                    af[mi], bg[ni], accG[mi][ni], 0, 0, 0);
                accU[mi][ni] = __builtin_amdgcn_mfma_f32_16x16x32_bf16(
                    af[mi], bu[ni], accU[mi][ni], 0, 0, 0);
            }
        __builtin_amdgcn_s_setprio(0);
    };

    // NPH = 128 half-K phases (128 % 3 == 2 -> epilogue of exactly 2).
    stage(0, 0);
    stage(1, 1);
    for (int ph = 0; ph + 4 < 128; ph += 3) {
        stage(2, ph + 2); W6(); BAR(); comp(0); BAR();
        stage(0, ph + 3); W6(); BAR(); comp(1); BAR();
        stage(1, ph + 4); W6(); BAR(); comp(2); BAR();
    }
    W3(); BAR(); comp(0);          // phase 126
    W0(); BAR(); comp(1);          // phase 127

    // ---- epilogue: SwiGLU ----
#pragma unroll
    for (int ni = 0; ni < 2; ++ni) {
        int col = n0 + wn + ni * 16 + (lane & 15);
        float gb = gbias[col], ub = ubias[col];
#pragma unroll
        for (int mi = 0; mi < 4; ++mi) {
#pragma unroll
            for (int j = 0; j < 4; ++j) {
                int row = m0 + wm + mi * 16 + ((lane >> 4) * 4) + j;
                float g = accG[mi][ni][j] + gb;
                float u = accU[mi][ni][j] + ub;
                float sig = 1.f / (1.f + __expf(-g));
                h[(size_t)row * INTER + col] = f2bf(g * sig * u);
            }
        }
    }
}

// ---------------------------------------------------------------------------
// Down GEMM: y = h @ Wd^T + bias (fp32). 512 thr, tile 128x128,
// ring-3 half-K phases (48 KB), counted vmcnt(4). Grid 512, XCD swizzle.
// ---------------------------------------------------------------------------
__global__ __launch_bounds__(512) void k_down(
    const unsigned short* __restrict__ h,    // [SEQ][INTER] bf16
    const unsigned short* __restrict__ wd,   // [HIDDEN][INTER] bf16
    const float* __restrict__ dbias,
    float* __restrict__ y)                   // [SEQ][HIDDEN] fp32
{
    __shared__ __align__(16) unsigned short A_[3][128 * 32];
    __shared__ __align__(16) unsigned short B_[3][128 * 32];

    const int orig = blockIdx.x;                  // 512 = 8 * 64
    const int swz  = (orig & 7) * 64 + (orig >> 3);
    const int mt   = swz & 15;
    const int nt   = swz >> 4;
    const int m0   = mt * 128;
    const int n0   = nt * 128;

    const int t    = threadIdx.x;
    const int lane = t & 63;
    const int wave = t >> 6;
    const int wm = (wave >> 2) * 64;
    const int wn = (wave & 3) * 32;

    const int srow = t >> 3;
    const int sl   = (t & 7) ^ (srow & 7);
    const int lrow = srow * 2 + (sl >> 2);
    const int lcolb = (sl & 3) * 16;

    const int sS   = ((((lane & 1) << 2) | (lane >> 4)) ^ ((lane >> 1) & 7)) * 16;
    const int lrh  = (lane & 15) >> 1;

    f32x4 acc[4][2];
#pragma unroll
    for (int mi = 0; mi < 4; ++mi)
#pragma unroll
        for (int ni = 0; ni < 2; ++ni)
            acc[mi][ni] = (f32x4){0.f, 0.f, 0.f, 0.f};

    auto stage = [&](int buf, int ph) {
        const int k0 = ph * 32;
        gload_lds16((const char*)(h  + (size_t)(m0 + lrow) * INTER + k0) + lcolb,
                    (char*)A_[buf] + t * 16);
        gload_lds16((const char*)(wd + (size_t)(n0 + lrow) * INTER + k0) + lcolb,
                    (char*)B_[buf] + t * 16);
    };

    auto comp = [&](int buf) {
        bf16x8 af[4], bd[2];
#pragma unroll
        for (int mi = 0; mi < 4; ++mi)
            af[mi] = *(const bf16x8*)((const char*)A_[buf] +
                        (wm / 2 + mi * 8 + lrh) * 128 + sS);
#pragma unroll
        for (int ni = 0; ni < 2; ++ni)
            bd[ni] = *(const bf16x8*)((const char*)B_[buf] +
                        (wn / 2 + ni * 8 + lrh) * 128 + sS);
        __builtin_amdgcn_s_setprio(1);
#pragma unroll
        for (int mi = 0; mi < 4; ++mi)
#pragma unroll
            for (int ni = 0; ni < 2; ++ni)
                acc[mi][ni] = __builtin_amdgcn_mfma_f32_16x16x32_bf16(
                    af[mi], bd[ni], acc[mi][ni], 0, 0, 0);
        __builtin_amdgcn_s_setprio(0);
    };

    // NPH = 344 (344 % 3 == 2).
    stage(0, 0);
    stage(1, 1);
    for (int ph = 0; ph + 4 < 344; ph += 3) {
        stage(2, ph + 2); W4(); BAR(); comp(0); BAR();
        stage(0, ph + 3); W4(); BAR(); comp(1); BAR();
        stage(1, ph + 4); W4(); BAR(); comp(2); BAR();
    }
    W2(); BAR(); comp(0);          // phase 342
    W0(); BAR(); comp(1);          // phase 343

#pragma unroll
    for (int ni = 0; ni < 2; ++ni) {
        int col = n0 + wn + ni * 16 + (lane & 15);
        float db = dbias[col];
#pragma unroll
        for (int mi = 0; mi < 4; ++mi) {
#pragma unroll
            for (int j = 0; j < 4; ++j) {
                int row = m0 + wm + mi * 16 + ((lane >> 4) * 4) + j;
                y[(size_t)row * HIDDEN + col] = acc[mi][ni][j] + db;
            }
        }
    }
}

// ---------------------------------------------------------------------------
extern "C" void kernel_launch(void* const* d_in, const int* in_sizes, int n_in,
                              void* d_out, int out_size, void* d_ws, size_t ws_size,
                              hipStream_t stream) {
    const float* x    = (const float*)d_in[0];
    const int*   gqw  = (const int*)d_in[1];
    const int*   gqz  = (const int*)d_in[2];
    const float* gsc  = (const float*)d_in[3];
    const float* gbia = (const float*)d_in[4];
    const int*   uqw  = (const int*)d_in[5];
    const int*   uqz  = (const int*)d_in[6];
    const float* usc  = (const float*)d_in[7];
    const float* ubia = (const float*)d_in[8];
    const int*   dqw  = (const int*)d_in[9];
    const int*   dqz  = (const int*)d_in[10];
    const float* dsc  = (const float*)d_in[11];
    const float* dbia = (const float*)d_in[12];
    float* y = (float*)d_out;

    const size_t N_XB = (size_t)SEQ * HIDDEN;
    const size_t N_H  = (size_t)SEQ * INTER;
    const size_t N_W  = (size_t)INTER * HIDDEN;

    unsigned short* xb  = (unsigned short*)d_ws;
    unsigned short* hh  = xb + N_XB;
    unsigned short* wgb = hh + N_H;
    unsigned short* wub = wgb + N_W;
    unsigned short* wdb = wgb;                 // reused after k_gate_up

    const int dq_blocks = (int)(N_W / 2048);   // 22016

    k_cvt_x<<<(SEQ * HIDDEN) / 1024, 256, 0, stream>>>(x, xb);
    k_dequant<<<dq_blocks, 256, 0, stream>>>(gqw, gqz, gsc, wgb);
    k_dequant<<<dq_blocks, 256, 0, stream>>>(uqw, uqz, usc, wub);
    k_gate_up<<<dim3(1376), 512, 0, stream>>>(xb, wgb, wub, gbia, ubia, hh);
    k_dequant<<<dq_blocks, 256, 0, stream>>>(dqw, dqz, dsc, wdb);
    k_down<<<dim3(512), 512, 0, stream>>>(hh, wdb, dbia, y);
}